// Round 1
// 1122.779 us; speedup vs baseline: 1.0811x; 1.0811x over previous
//
#include <hip/hip_runtime.h>

#define D_IN 2312
#define HID  800
#define NCLS 10
#define BATCH 128
#define TSTEPS 300
#define WIN  50

#define MT 64                              // block tile rows (2 waves x 32)
#define NT 32
#define BKK 16
#define NTM 100                            // 6400/64
#define NTN 25                             // 800/32, exact
#define GEMM_BLOCKS (NTM * NTN)            // 2500 two-wave tiles
#define PASTE_BLOCKS 2048
#define BLK 128
#define TOTQ (BATCH * D_IN * (TSTEPS / 4)) // 22,195,200 float4s of X

// ---------------------------------------------------------------------------
// Fused: blocks [0,2500) = 2-wave 64x32 fp32 GEMM tiles (wave w owns rows
// w*32..w*32+31 with the SAME 32x32 micro-kernel as the proven round-5 kernel
// -> bit-identical P). 2-wave blocks lift the 16-workgroup/CU occupancy cap
// (was 16 waves/CU with 1-wave blocks -> now up to 32) and share one B-tile
// stage between both waves. blocks [2500,+2048) = grid-stride paste of X.
// ---------------------------------------------------------------------------
__global__ __launch_bounds__(BLK) void fused_kernel(
    const float* __restrict__ inp,   // [B][D_IN][WIN]
    const float* __restrict__ W1,    // [HID][D_IN]
    const int*   __restrict__ idx,   // [B]
    float*       __restrict__ P,     // [6400][HID]
    float*       __restrict__ outX)  // [B][D_IN][T]
{
  __shared__ float As[BKK][MT];       // 4 KB
  __shared__ float Bs[BKK][NT + 4];   // 2.25 KB

  int t  = threadIdx.x;
  int bx = blockIdx.x;

  if (bx < GEMM_BLOCKS) {
    int nt = bx / NTM;                 // consecutive blocks share n-tile (L2)
    int mt = bx - nt * NTM;
    int m0 = mt * MT, n0 = nt * NT;

    // A staging: 64 rows x 16 k staged by 128 threads (8 k's each),
    // coalesced along m (s-contiguous)
    int am = t & 63;
    int ah = t >> 6;                   // 0..1 -> k-half (== wave id)
    int r  = m0 + am;
    int bb = r / 50, ss = r - bb * 50;
    const float* aptr = inp + (size_t)bb * (D_IN * WIN) + ss;   // + k*50

    // B staging: 32 n x 16 k by 128 threads (4 each), coalesced along k
    int bn = t >> 4;                   // 0..7
    int bk = t & 15;                   // 0..15

    int l  = t & 63;
    int lm = l & 7;                    // m micro-group
    int ln = l >> 3;                   // n micro-group
    int tm = ah * 32 + lm * 4;         // wave ah owns rows [ah*32, ah*32+32)
    int tn = ln * 4;

    float aN[8], bN[4];
#pragma unroll
    for (int q = 0; q < 8; ++q) aN[q] = aptr[(ah * 8 + q) * WIN];
#pragma unroll
    for (int p = 0; p < 4; ++p)
      bN[p] = W1[(size_t)(n0 + bn + 8 * p) * D_IN + bk];

    float acc[4][4] = {};

    for (int k0 = 0; k0 < D_IN; k0 += BKK) {   // 145 slabs, last partial
#pragma unroll
      for (int q = 0; q < 8; ++q) As[ah * 8 + q][am] = aN[q];
#pragma unroll
      for (int p = 0; p < 4; ++p) Bs[bk][bn + 8 * p] = bN[p];
      __syncthreads();

      int kn0 = k0 + BKK;
      if (kn0 < D_IN) {
#pragma unroll
        for (int q = 0; q < 8; ++q) {
          int kk = kn0 + ah * 8 + q;
          aN[q] = (kk < D_IN) ? aptr[kk * WIN] : 0.f;
        }
#pragma unroll
        for (int p = 0; p < 4; ++p) {
          int kk = kn0 + bk;
          bN[p] = (kk < D_IN) ? W1[(size_t)(n0 + bn + 8 * p) * D_IN + kk] : 0.f;
        }
      }

#pragma unroll
      for (int kk = 0; kk < BKK; ++kk) {
        float4 A0 = *(const float4*)&As[kk][tm];
        float4 B0 = *(const float4*)&Bs[kk][tn];
        float av[4] = {A0.x, A0.y, A0.z, A0.w};
        float bv[4] = {B0.x, B0.y, B0.z, B0.w};
#pragma unroll
        for (int i = 0; i < 4; ++i)
#pragma unroll
          for (int j = 0; j < 4; ++j)
            acc[i][j] += av[i] * bv[j];
      }
      __syncthreads();
    }

#pragma unroll
    for (int i = 0; i < 4; ++i) {
      int row = m0 + tm + i;
      *(float4*)&P[(size_t)row * HID + n0 + tn] =
          make_float4(acc[i][0], acc[i][1], acc[i][2], acc[i][3]);
    }
  } else {
    // ---- paste path: X = zeros with input window pasted at idx[b] ----
    int tid = (bx - GEMM_BLOCKS) * BLK + t;
    const int stride = PASTE_BLOCKS * BLK;
    for (int i = tid; i < TOTQ; i += stride) {
      int q  = i % 75;
      int rd = i / 75;
      int b  = rd / D_IN;
      int d  = rd - b * D_IN;
      int ib = idx[b];
      const float* ip = inp + (size_t)b * (D_IN * WIN) + (size_t)d * WIN;
      int t0 = q * 4;
      float v[4];
#pragma unroll
      for (int e = 0; e < 4; ++e) {
        unsigned w = (unsigned)(t0 + e - ib);
        v[e] = (w < (unsigned)WIN) ? ip[w] : 0.f;
      }
      *(float4*)&outX[(size_t)rd * TSTEPS + t0] = make_float4(v[0], v[1], v[2], v[3]);
    }
  }
}

// ---------------------------------------------------------------------------
// Recurrence v4 — single-pass. One wave per batch (latency-bound, 1 wave/CU,
// so occupancy is irrelevant -> __launch_bounds__(64,1) unlocks the full VGPR
// file and everything lives in registers). vs v3:
//   * h2 chain merged into the main loop (same per-step FP sequence as the
//     old deferred replay -> bit-identical), removing the duplicated 300-step
//     replay shell and the sM/sSteps LDS round-trip.
//   * P row for step+1 prefetched unconditionally; the cs-gate becomes a
//     multiply by {0,1} (exact), taking the global load off the serial chain.
//   * Wc held in registers (wcr[13]) instead of LDS.
// ---------------------------------------------------------------------------
__global__ __launch_bounds__(64, 1) void recur_kernel(
    const float* __restrict__ P,    // [6400][HID]
    const float* __restrict__ W2,   // [NCLS][HID]
    const float* __restrict__ b2,   // [NCLS]
    const float* __restrict__ Wc,   // [HID+4]
    const float* __restrict__ bc,   // [1]
    const float* __restrict__ b1,   // [HID]
    const int*   __restrict__ idx,  // [B]
    float*       __restrict__ out)  // [B][NCLS]
{
  __shared__ float sW2row[NCLS][832];           // 33.3 KB, row-major, 2-way-free

  int L = threadIdx.x;
  int b = blockIdx.x;

#pragma unroll
  for (int c = 0; c < NCLS; ++c)
    for (int base = 0; base < 832; base += 64) {
      int j = base + L;
      sW2row[c][j] = (j < HID) ? W2[c * HID + j] : 0.f;
    }

  int myidx = idx[b];
  const float* Pb = P + (size_t)b * WIN * HID;

  float m[13], b1r[13], wcr[13];
  unsigned smask = 0;
#pragma unroll
  for (int rr = 0; rr < 13; ++rr) {
    int j = L + 64 * rr;
    m[rr]   = 0.f;
    b1r[rr] = (j < HID) ? b1[j] : 0.f;
    wcr[rr] = (j < HID) ? Wc[j] : 0.f;
  }

  float cm = 0.f, cs = 0.f, bgt = 1.f;
  float bc0 = bc[0];
  float wf0 = Wc[HID], wf1 = Wc[HID + 1], wf2 = Wc[HID + 2], wf3 = Wc[HID + 3];

  float h2m[10], h2s[10], sum2[10], b2r[10];
#pragma unroll
  for (int c = 0; c < NCLS; ++c) { h2m[c] = 0.f; h2s[c] = 0.f; sum2[c] = 0.f; b2r[c] = b2[c]; }

  __syncthreads();

  // prefetch P row for step 0
  float cur[13];
  {
    unsigned w0 = (unsigned)(0 - myidx);
    if (w0 < (unsigned)WIN) {
      const float* Pr = Pb + (size_t)w0 * HID;
#pragma unroll
      for (int rr = 0; rr < 13; ++rr) {
        int j = L + 64 * rr;
        cur[rr] = (j < HID) ? Pr[j] : 0.f;
      }
    } else {
#pragma unroll
      for (int rr = 0; rr < 13; ++rr) cur[rr] = 0.f;
    }
  }

  for (int step = 0; step < TSTEPS; ++step) {
    float gate = (step == 0) ? 1.f : cs;

    // unconditional prefetch of next step's P row (independent of this
    // step's chain; gating is applied at use as *gate, exact for {0,1})
    float nxt[13];
    {
      unsigned wn = (unsigned)(step + 1 - myidx);
      if (wn < (unsigned)WIN) {
        const float* Pr = Pb + (size_t)wn * HID;
#pragma unroll
        for (int rr = 0; rr < 13; ++rr) {
          int j = L + 64 * rr;
          nxt[rr] = (j < HID) ? Pr[j] : 0.f;
        }
      } else {
#pragma unroll
        for (int rr = 0; rr < 13; ++rr) nxt[rr] = 0.f;
      }
    }

    unsigned nmask = 0;
#pragma unroll
    for (int rr = 0; rr < 13; ++rr) {
      float mprev = ((smask >> rr) & 1u) ? 0.f : m[rr] * 0.1f;
      float mv = mprev + cur[rr] * gate + b1r[rr];
      m[rr] = mv;
      nmask |= (mv > 0.5f) ? (1u << rr) : 0u;
    }
    smask = nmask;

    unsigned long long ball = __ballot(smask != 0u);

    float ctrl = 0.f;
    float dot[10];
#pragma unroll
    for (int c = 0; c < NCLS; ++c) dot[c] = 0.f;

    if (ball) {
      // ctrl dot: branchless FMA over own units, all-register
      float cacc = 0.f;
#pragma unroll
      for (int rr = 0; rr < 13; ++rr) {
        float f = (float)((smask >> rr) & 1u);
        cacc = fmaf(f, wcr[rr], cacc);
      }
      cacc += __shfl_xor(cacc, 1);
      cacc += __shfl_xor(cacc, 2);
      cacc += __shfl_xor(cacc, 4);
      cacc += __shfl_xor(cacc, 8);
      cacc += __shfl_xor(cacc, 16);
      cacc += __shfl_xor(cacc, 32);
      ctrl = cacc;

      // h2 dot (was the deferred replay; same FMA + butterfly order)
#pragma unroll
      for (int rr = 0; rr < 13; ++rr) {
        float f = (float)((smask >> rr) & 1u);
        int j = L + 64 * rr;
#pragma unroll
        for (int c = 0; c < NCLS; ++c)
          dot[c] = fmaf(f, sW2row[c][j], dot[c]);
      }
#pragma unroll
      for (int c = 0; c < NCLS; ++c) {
        float v = dot[c];
        v += __shfl_xor(v, 1);
        v += __shfl_xor(v, 2);
        v += __shfl_xor(v, 4);
        v += __shfl_xor(v, 8);
        v += __shfl_xor(v, 16);
        v += __shfl_xor(v, 32);
        dot[c] = v;
      }
    }

    // ctrl neuron + budget (uses prev-step cs, then updates it)
    bgt += (cs == 1.f) ? 1.f : 0.f;
    float fq = wf0;
    if ((step & 1) == 0)   fq += wf1;
    if (step % 10 == 0)    fq += wf2;
    if (step % 100 == 0)   fq += wf3;
    float cv = (cs != 0.f ? 0.f : cm * 0.1f) + ctrl + fq + bc0;
    cm = cv;
    cs = (cv > 0.5f) ? 1.f : 0.f;

    // h2 membrane update every step (dot==0 on silent steps)
#pragma unroll
    for (int c = 0; c < NCLS; ++c) {
      float v = (h2s[c] != 0.f ? 0.f : h2m[c] * 0.1f) + dot[c] + b2r[c];
      h2m[c] = v;
      h2s[c] = (v > 0.5f) ? 1.f : 0.f;
      sum2[c] += h2s[c];
    }

#pragma unroll
    for (int rr = 0; rr < 13; ++rr) cur[rr] = nxt[rr];
  }

  if (L == 0) {
#pragma unroll
    for (int c = 0; c < NCLS; ++c) out[b * NCLS + c] = sum2[c] / bgt;
  }
}

// ---------------------------------------------------------------------------
extern "C" void kernel_launch(void* const* d_in, const int* in_sizes, int n_in,
                              void* d_out, int out_size, void* d_ws, size_t ws_size,
                              hipStream_t stream) {
  const float* inp = (const float*)d_in[0];
  const int*   idx = (const int*)d_in[2];
  const float* W1  = (const float*)d_in[3];
  const float* b1  = (const float*)d_in[4];
  const float* W2  = (const float*)d_in[5];
  const float* b2  = (const float*)d_in[6];
  const float* Wc  = (const float*)d_in[7];
  const float* bc  = (const float*)d_in[8];

  float* out = (float*)d_out;   // [0,1280): rate ; then X
  float* P   = (float*)d_ws;    // [6400][800] fp32 = 20.48 MB

  fused_kernel<<<GEMM_BLOCKS + PASTE_BLOCKS, BLK, 0, stream>>>(
      inp, W1, idx, P, out + BATCH * NCLS);

  recur_kernel<<<BATCH, 64, 0, stream>>>(P, W2, b2, Wc, bc, b1, idx, out);
}